// Round 1
// baseline (116.396 us; speedup 1.0000x reference)
//
#include <hip/hip_runtime.h>
#include <cstddef>

#define Bq 16
#define TEq 128
#define TDq 128
#define Hq 256

#define kC2  2.8853900817779268f  /* 2*log2(e) */
#define kL2E 1.4426950408889634f

static __device__ __forceinline__ float fast_rcp(float x) {
#if __has_builtin(__builtin_amdgcn_rcpf)
    return __builtin_amdgcn_rcpf(x);
#else
    return 1.0f / x;
#endif
}

static __device__ __forceinline__ float fast_exp2(float x) {
#if __has_builtin(__builtin_amdgcn_exp2f)
    return __builtin_amdgcn_exp2f(x);
#else
    return exp2f(x);
#endif
}

// ---------------------------------------------------------------------------
// K1: orthogonalize. thread = (b,h); exclusive cumsum of x over t, then
// o = x - ((x*s)/(x*x))*x  (written exactly as the reference computes it).
// Layout stays [B,TE,H].
// ---------------------------------------------------------------------------
__global__ __launch_bounds__(64) void k_ortho(const float* __restrict__ enc,
                                              float* __restrict__ out) {
    const int idx = blockIdx.x * 64 + threadIdx.x;   // 0..B*H-1
    const int b = idx >> 8;
    const int h = idx & 255;
    const float* p = enc + (size_t)b * TEq * Hq + h;
    float* q = out + (size_t)b * TEq * Hq + h;
    float s = 0.0f;
#pragma unroll 8
    for (int t = 0; t < TEq; ++t) {
        const float x = p[(size_t)t * Hq];
        const float r = (x * s) / (x * x);
        q[(size_t)t * Hq] = x - r * x;
        s += x;
    }
}

// ---------------------------------------------------------------------------
// K2: two GEMMs, C = A[2048,256] @ W[256,256].  z=0: was = enc_o@W_a (scaled
// by 2*log2e for the tanh path), z=1: uah = dec@U_a.
// 64x64 tile / 256 threads / 4x4 per thread / BK=16.
// ---------------------------------------------------------------------------
__global__ __launch_bounds__(256) void k_gemm2(const float* __restrict__ A0,
                                               const float* __restrict__ A1,
                                               const float* __restrict__ W0,
                                               const float* __restrict__ W1,
                                               float* __restrict__ Cw,
                                               float* __restrict__ Cu) {
    const int z = blockIdx.z;
    const float* __restrict__ A = z ? A1 : A0;
    const float* __restrict__ W = z ? W1 : W0;
    float* __restrict__ C = z ? Cu : Cw;
    const float scale = z ? 1.0f : kC2;

    const int bm = blockIdx.y * 64;
    const int bn = blockIdx.x * 64;

    __shared__ float sA[16][68];   // [k][m], +4 pad keeps b128 reads aligned
    __shared__ float sB[16][64];   // [k][n]

    const int tid = threadIdx.x;
    const int tx = tid & 15;          // 4 cols each
    const int ty = tid >> 4;          // 4 rows each
    const int arow = tid >> 2;        // 0..63
    const int akcol = (tid & 3) << 2; // 0,4,8,12
    const int brow = tid >> 4;        // 0..15
    const int bcol = (tid & 15) << 2; // 0..60

    float acc[4][4] = {};

    for (int k0 = 0; k0 < Hq; k0 += 16) {
        const float4 av = *(const float4*)(A + (size_t)(bm + arow) * Hq + k0 + akcol);
        const float4 bv = *(const float4*)(W + (size_t)(k0 + brow) * Hq + bn + bcol);
        __syncthreads();
        sA[akcol + 0][arow] = av.x;
        sA[akcol + 1][arow] = av.y;
        sA[akcol + 2][arow] = av.z;
        sA[akcol + 3][arow] = av.w;
        *(float4*)&sB[brow][bcol] = bv;
        __syncthreads();
#pragma unroll
        for (int k = 0; k < 16; ++k) {
            const float4 a4 = *(const float4*)&sA[k][ty << 2];
            const float4 b4 = *(const float4*)&sB[k][tx << 2];
            const float aarr[4] = {a4.x, a4.y, a4.z, a4.w};
            const float barr[4] = {b4.x, b4.y, b4.z, b4.w};
#pragma unroll
            for (int i = 0; i < 4; ++i)
#pragma unroll
                for (int j = 0; j < 4; ++j)
                    acc[i][j] = fmaf(aarr[i], barr[j], acc[i][j]);
        }
    }
#pragma unroll
    for (int i = 0; i < 4; ++i) {
        float4 o;
        o.x = acc[i][0] * scale;
        o.y = acc[i][1] * scale;
        o.z = acc[i][2] * scale;
        o.w = acc[i][3] * scale;
        *(float4*)(C + (size_t)(bm + (ty << 2) + i) * Hq + bn + (tx << 2)) = o;
    }
}

// ---------------------------------------------------------------------------
// K3: energies + softmax + context, fused. Block = (b, 4 consecutive d).
// Wave w handles d = d0+w: 4 sub-groups of 16 lanes each own one e at a time,
// each lane covers 16 h (4 interleaved float4 chunks -> coalesced was reads).
// tanh(z) = 1 - 2/(exp2(C2*z)+1); energy = Vsum - 2*sum(v*r).
// was is pre-scaled by C2 (K2 epilogue); uah scaled at LDS load.
// ---------------------------------------------------------------------------
__global__ __launch_bounds__(256) void k_attn(const float* __restrict__ was,
                                              const float* __restrict__ uah,
                                              const float* __restrict__ enc_o,
                                              const float* __restrict__ Va,
                                              float* __restrict__ c_out,
                                              float* __restrict__ e_out) {
    const int b = blockIdx.y;
    const int d0 = blockIdx.x << 2;

    __shared__ float uahs[4][Hq];
    __shared__ float Vs[Hq];
    __shared__ float wts[4][TEq];   // energies, then softmax weights

    const int tid = threadIdx.x;
    const int w = tid >> 6;        // wave 0..3 -> d = d0+w
    const int lane = tid & 63;

    Vs[tid] = Va[tid];
#pragma unroll
    for (int j = 0; j < 4; ++j)
        uahs[j][tid] = uah[((size_t)b * TDq + d0 + j) * Hq + tid] * kC2;
    __syncthreads();

    const int g = lane >> 4;       // sub-group 0..3
    const int ll = lane & 15;      // lane within sub-group

    // Vsum (all lanes)
    float vs = Vs[lane] + Vs[lane + 64] + Vs[lane + 128] + Vs[lane + 192];
#pragma unroll
    for (int m = 1; m <= 32; m <<= 1) vs += __shfl_xor(vs, m);

    // preload this lane's u/v fragments: h = c*64 + ll*4 + i
    float4 ur[4], vr[4];
#pragma unroll
    for (int c = 0; c < 4; ++c) {
        ur[c] = *(const float4*)&uahs[w][c * 64 + (ll << 2)];
        vr[c] = *(const float4*)&Vs[c * 64 + (ll << 2)];
    }

    const float* wasb = was + (size_t)b * TEq * Hq;

    for (int ei = 0; ei < 32; ++ei) {
        const int e = (g << 5) + ei;
        const float* wp = wasb + (size_t)e * Hq + (ll << 2);
        float acc = 0.0f;
#pragma unroll
        for (int c = 0; c < 4; ++c) {
            const float4 wv = *(const float4*)(wp + c * 64);
            const float wf[4] = {wv.x, wv.y, wv.z, wv.w};
            const float uf[4] = {ur[c].x, ur[c].y, ur[c].z, ur[c].w};
            const float vf[4] = {vr[c].x, vr[c].y, vr[c].z, vr[c].w};
#pragma unroll
            for (int i = 0; i < 4; ++i) {
                const float s = wf[i] + uf[i];          // C2*(was+uah)
                const float t = fast_exp2(s);           // e^{2z}
                const float r = fast_rcp(t + 1.0f);
                acc = fmaf(vf[i], r, acc);
            }
        }
        acc += __shfl_xor(acc, 1);
        acc += __shfl_xor(acc, 2);
        acc += __shfl_xor(acc, 4);
        acc += __shfl_xor(acc, 8);
        if (ll == 0) wts[w][e] = vs - 2.0f * acc;
    }

    // softmax over the 128 energies of this wave's d
    float v0 = wts[w][lane];
    float v1 = wts[w][lane + 64];
    float mx = fmaxf(v0, v1);
#pragma unroll
    for (int m = 1; m <= 32; m <<= 1) mx = fmaxf(mx, __shfl_xor(mx, m));
    const float e0 = fast_exp2((v0 - mx) * kL2E);
    const float e1 = fast_exp2((v1 - mx) * kL2E);
    float sm = e0 + e1;
#pragma unroll
    for (int m = 1; m <= 32; m <<= 1) sm += __shfl_xor(sm, m);
    const float inv = fast_rcp(sm);
    const float w0 = e0 * inv;
    const float w1 = e1 * inv;
    wts[w][lane] = w0;
    wts[w][lane + 64] = w1;
    {
        const size_t eb = ((size_t)b * TDq + d0 + w) * TEq;
        e_out[eb + lane] = w0;
        e_out[eb + lane + 64] = w1;
    }
    __syncthreads();

    // context: c[b,d0+j,h=tid] = sum_e wts[j][e] * enc_o[b,e,h]
    float a0 = 0.0f, a1 = 0.0f, a2 = 0.0f, a3 = 0.0f;
    const float* ep = enc_o + (size_t)b * TEq * Hq + tid;
#pragma unroll 8
    for (int e = 0; e < TEq; ++e) {
        const float evv = ep[(size_t)e * Hq];
        a0 = fmaf(wts[0][e], evv, a0);
        a1 = fmaf(wts[1][e], evv, a1);
        a2 = fmaf(wts[2][e], evv, a2);
        a3 = fmaf(wts[3][e], evv, a3);
    }
    const size_t cb = ((size_t)b * TDq + d0) * Hq + tid;
    c_out[cb] = a0;
    c_out[cb + Hq] = a1;
    c_out[cb + 2 * Hq] = a2;
    c_out[cb + 3 * Hq] = a3;
}

extern "C" void kernel_launch(void* const* d_in, const int* in_sizes, int n_in,
                              void* d_out, int out_size, void* d_ws, size_t ws_size,
                              hipStream_t stream) {
    const float* enc = (const float*)d_in[0];   // [16,128,256]
    const float* dec = (const float*)d_in[1];   // [16,128,256]
    const float* Wa  = (const float*)d_in[2];   // [256,256]
    const float* Ua  = (const float*)d_in[3];   // [256,256]
    const float* Va  = (const float*)d_in[4];   // [256,1]

    float* c_out = (float*)d_out;                        // [16,128,256]
    float* e_out = c_out + (size_t)Bq * TDq * Hq;        // [16,128,128]

    float* enc_o = (float*)d_ws;                         // 2 MB
    float* wasb  = enc_o + (size_t)Bq * TEq * Hq;        // 2 MB (pre-scaled by 2*log2e)
    float* uahb  = wasb + (size_t)Bq * TEq * Hq;         // 2 MB

    k_ortho<<<dim3((Bq * Hq) / 64), dim3(64), 0, stream>>>(enc, enc_o);
    k_gemm2<<<dim3(Hq / 64, (Bq * TEq) / 64, 2), dim3(256), 0, stream>>>(
        enc_o, dec, Wa, Ua, wasb, uahb);
    k_attn<<<dim3(TDq / 4, Bq), dim3(256), 0, stream>>>(
        wasb, uahb, enc_o, Va, c_out, e_out);
}

// Round 2
// 106.213 us; speedup vs baseline: 1.0959x; 1.0959x over previous
//
#include <hip/hip_runtime.h>
#include <cstddef>

#define Bq 16
#define TEq 128
#define TDq 128
#define Hq 256

#define kC2  2.8853900817779268f  /* 2*log2(e) */
#define kL2E 1.4426950408889634f

static __device__ __forceinline__ float fast_rcp(float x) {
#if __has_builtin(__builtin_amdgcn_rcpf)
    return __builtin_amdgcn_rcpf(x);
#else
    return 1.0f / x;
#endif
}

static __device__ __forceinline__ float fast_exp2(float x) {
#if __has_builtin(__builtin_amdgcn_exp2f)
    return __builtin_amdgcn_exp2f(x);
#else
    return exp2f(x);
#endif
}

// ---------------------------------------------------------------------------
// K1: orthogonalize. Exclusive cumsum over TE split into 8 chunks of 16 per
// (b,h); chunk partials exchanged via LDS; x held in registers (loaded once).
// Block = 256 thr = 8 chunks x 32 h. Grid = (H/32, B) = (8,16) = 128 blocks.
// ---------------------------------------------------------------------------
__global__ __launch_bounds__(256) void k_ortho(const float* __restrict__ enc,
                                               float* __restrict__ out) {
    const int b = blockIdx.y;
    const int hg = blockIdx.x;            // 0..7
    const int tid = threadIdx.x;
    const int hl = tid & 31;
    const int ck = tid >> 5;              // chunk 0..7 (16 t each)
    const int h = (hg << 5) + hl;

    __shared__ float sums[8][33];

    const float* p = enc + ((size_t)b * TEq + ck * 16) * Hq + h;
    float xs[16];
#pragma unroll
    for (int i = 0; i < 16; ++i) xs[i] = p[(size_t)i * Hq];
    float tot = 0.0f;
#pragma unroll
    for (int i = 0; i < 16; ++i) tot += xs[i];
    sums[ck][hl] = tot;
    __syncthreads();

    float s = 0.0f;
    for (int c = 0; c < ck; ++c) s += sums[c][hl];   // exclusive chunk prefix

    float* q = out + ((size_t)b * TEq + ck * 16) * Hq + h;
#pragma unroll
    for (int i = 0; i < 16; ++i) {
        const float x = xs[i];
        const float r = (x * s) / (x * x);           // exact div, matches ref
        q[(size_t)i * Hq] = x - r * x;
        s += x;
    }
}

// ---------------------------------------------------------------------------
// K2: two GEMMs, C = A[2048,256] @ W[256,256].  z=0: was = enc_o@W_a (scaled
// by 2*log2e), z=1: uah = dec@U_a.
// 32x64 tile / 256 threads / 2x4 per thread / BK=16. Grid (4,64,2)=512 blocks
// -> 2 blocks/CU, 8 waves/CU.
// ---------------------------------------------------------------------------
__global__ __launch_bounds__(256) void k_gemm2(const float* __restrict__ A0,
                                               const float* __restrict__ A1,
                                               const float* __restrict__ W0,
                                               const float* __restrict__ W1,
                                               float* __restrict__ Cw,
                                               float* __restrict__ Cu) {
    const int z = blockIdx.z;
    const float* __restrict__ A = z ? A1 : A0;
    const float* __restrict__ W = z ? W1 : W0;
    float* __restrict__ C = z ? Cu : Cw;
    const float scale = z ? 1.0f : kC2;

    const int bm = blockIdx.y * 32;
    const int bn = blockIdx.x * 64;

    __shared__ float sA[16][33];   // [k][m] (+1 pad)
    __shared__ float sB[16][64];   // [k][n]

    const int tid = threadIdx.x;
    const int tx = tid & 15;       // n: 4 cols each
    const int ty = tid >> 4;       // m: 2 rows each
    const int arow = tid >> 3;           // 0..31
    const int akcol = (tid & 7) << 1;    // 0,2,..,14
    const int brow = tid >> 4;           // 0..15
    const int bcol = (tid & 15) << 2;    // 0..60

    float acc[2][4] = {};

    for (int k0 = 0; k0 < Hq; k0 += 16) {
        const float2 av = *(const float2*)(A + (size_t)(bm + arow) * Hq + k0 + akcol);
        const float4 bv = *(const float4*)(W + (size_t)(k0 + brow) * Hq + bn + bcol);
        __syncthreads();
        sA[akcol + 0][arow] = av.x;
        sA[akcol + 1][arow] = av.y;
        *(float4*)&sB[brow][bcol] = bv;
        __syncthreads();
#pragma unroll
        for (int k = 0; k < 16; ++k) {
            const float a0 = sA[k][ty << 1];
            const float a1 = sA[k][(ty << 1) + 1];
            const float4 b4 = *(const float4*)&sB[k][tx << 2];
            acc[0][0] = fmaf(a0, b4.x, acc[0][0]);
            acc[0][1] = fmaf(a0, b4.y, acc[0][1]);
            acc[0][2] = fmaf(a0, b4.z, acc[0][2]);
            acc[0][3] = fmaf(a0, b4.w, acc[0][3]);
            acc[1][0] = fmaf(a1, b4.x, acc[1][0]);
            acc[1][1] = fmaf(a1, b4.y, acc[1][1]);
            acc[1][2] = fmaf(a1, b4.z, acc[1][2]);
            acc[1][3] = fmaf(a1, b4.w, acc[1][3]);
        }
    }
#pragma unroll
    for (int i = 0; i < 2; ++i) {
        float4 o;
        o.x = acc[i][0] * scale;
        o.y = acc[i][1] * scale;
        o.z = acc[i][2] * scale;
        o.w = acc[i][3] * scale;
        *(float4*)(C + (size_t)(bm + (ty << 1) + i) * Hq + bn + (tx << 2)) = o;
    }
}

// ---------------------------------------------------------------------------
// K3: energies + softmax + context. Block = (b, 2 d's); wave w: d-local=w>>1,
// e-half=w&1. 4 sub-groups of 16 lanes per wave each own one e at a time,
// each lane covers 16 h (4 interleaved float4 chunks).
// tanh(z) = 1 - 2/(exp2(C2*z)+1); energy = Vsum - 2*sum(v*r).
// was pre-scaled by C2 (K2 epilogue); uah scaled at LDS load.
// Grid (TD/2, B) = (64,16) = 1024 blocks -> 4 blocks/CU, 16 waves/CU.
// ---------------------------------------------------------------------------
__global__ __launch_bounds__(256) void k_attn(const float* __restrict__ was,
                                              const float* __restrict__ uah,
                                              const float* __restrict__ enc_o,
                                              const float* __restrict__ Va,
                                              float* __restrict__ c_out,
                                              float* __restrict__ e_out) {
    const int b = blockIdx.y;
    const int d0 = blockIdx.x << 1;

    __shared__ float uahs[2][Hq];
    __shared__ float Vs[Hq];
    __shared__ float wts[2][TEq];   // energies, then softmax weights

    const int tid = threadIdx.x;
    const int w = tid >> 6;         // wave 0..3
    const int lane = tid & 63;
    const int dl = w >> 1;          // d-local 0..1
    const int half = w & 1;         // e-half

    Vs[tid] = Va[tid];
#pragma unroll
    for (int j = 0; j < 2; ++j)
        uahs[j][tid] = uah[((size_t)b * TDq + d0 + j) * Hq + tid] * kC2;
    __syncthreads();

    const int g = lane >> 4;        // sub-group 0..3
    const int ll = lane & 15;

    // Vsum (all lanes, redundant across waves)
    float vs = Vs[lane] + Vs[lane + 64] + Vs[lane + 128] + Vs[lane + 192];
#pragma unroll
    for (int m = 1; m <= 32; m <<= 1) vs += __shfl_xor(vs, m);

    // preload u/v fragments: h = c*64 + ll*4 + i
    float4 ur[4], vr[4];
#pragma unroll
    for (int c = 0; c < 4; ++c) {
        ur[c] = *(const float4*)&uahs[dl][c * 64 + (ll << 2)];
        vr[c] = *(const float4*)&Vs[c * 64 + (ll << 2)];
    }

    const float* wasb = was + (size_t)b * TEq * Hq;

    for (int ei = 0; ei < 16; ++ei) {
        const int e = (half << 6) + (g << 4) + ei;
        const float* wp = wasb + (size_t)e * Hq + (ll << 2);
        float acc = 0.0f;
#pragma unroll
        for (int c = 0; c < 4; ++c) {
            const float4 wv = *(const float4*)(wp + c * 64);
            const float wf[4] = {wv.x, wv.y, wv.z, wv.w};
            const float uf[4] = {ur[c].x, ur[c].y, ur[c].z, ur[c].w};
            const float vf[4] = {vr[c].x, vr[c].y, vr[c].z, vr[c].w};
#pragma unroll
            for (int i = 0; i < 4; ++i) {
                const float s = wf[i] + uf[i];          // C2*(was+uah)
                const float t = fast_exp2(s);           // e^{2z}
                const float r = fast_rcp(t + 1.0f);
                acc = fmaf(vf[i], r, acc);
            }
        }
        acc += __shfl_xor(acc, 1);
        acc += __shfl_xor(acc, 2);
        acc += __shfl_xor(acc, 4);
        acc += __shfl_xor(acc, 8);
        if (ll == 0) wts[dl][e] = vs - 2.0f * acc;
    }
    __syncthreads();

    // softmax: waves 0,1 handle d = d0 + w
    if (w < 2) {
        const float v0 = wts[w][lane];
        const float v1 = wts[w][lane + 64];
        float mx = fmaxf(v0, v1);
#pragma unroll
        for (int m = 1; m <= 32; m <<= 1) mx = fmaxf(mx, __shfl_xor(mx, m));
        const float e0 = fast_exp2((v0 - mx) * kL2E);
        const float e1 = fast_exp2((v1 - mx) * kL2E);
        float sm = e0 + e1;
#pragma unroll
        for (int m = 1; m <= 32; m <<= 1) sm += __shfl_xor(sm, m);
        const float inv = fast_rcp(sm);
        const float w0 = e0 * inv;
        const float w1 = e1 * inv;
        wts[w][lane] = w0;
        wts[w][lane + 64] = w1;
        const size_t eb = ((size_t)b * TDq + d0 + w) * TEq;
        e_out[eb + lane] = w0;
        e_out[eb + lane + 64] = w1;
    }
    __syncthreads();

    // context: c[b,d0+j,h=tid] = sum_e wts[j][e] * enc_o[b,e,h]
    float a0 = 0.0f, a1 = 0.0f;
    const float* ep = enc_o + (size_t)b * TEq * Hq + tid;
#pragma unroll 8
    for (int e = 0; e < TEq; ++e) {
        const float evv = ep[(size_t)e * Hq];
        a0 = fmaf(wts[0][e], evv, a0);
        a1 = fmaf(wts[1][e], evv, a1);
    }
    const size_t cb = ((size_t)b * TDq + d0) * Hq + tid;
    c_out[cb] = a0;
    c_out[cb + Hq] = a1;
}

extern "C" void kernel_launch(void* const* d_in, const int* in_sizes, int n_in,
                              void* d_out, int out_size, void* d_ws, size_t ws_size,
                              hipStream_t stream) {
    const float* enc = (const float*)d_in[0];   // [16,128,256]
    const float* dec = (const float*)d_in[1];   // [16,128,256]
    const float* Wa  = (const float*)d_in[2];   // [256,256]
    const float* Ua  = (const float*)d_in[3];   // [256,256]
    const float* Va  = (const float*)d_in[4];   // [256,1]

    float* c_out = (float*)d_out;                        // [16,128,256]
    float* e_out = c_out + (size_t)Bq * TDq * Hq;        // [16,128,128]

    float* enc_o = (float*)d_ws;                         // 2 MB
    float* wasb  = enc_o + (size_t)Bq * TEq * Hq;        // 2 MB (pre-scaled by 2*log2e)
    float* uahb  = wasb + (size_t)Bq * TEq * Hq;         // 2 MB

    k_ortho<<<dim3(Hq / 32, Bq), dim3(256), 0, stream>>>(enc, enc_o);
    k_gemm2<<<dim3(Hq / 64, (Bq * TEq) / 32, 2), dim3(256), 0, stream>>>(
        enc_o, dec, Wa, Ua, wasb, uahb);
    k_attn<<<dim3(TDq / 2, Bq), dim3(256), 0, stream>>>(
        wasb, uahb, enc_o, Va, c_out, e_out);
}